// Round 7
// baseline (1096.809 us; speedup 1.0000x reference)
//
#include <hip/hip_runtime.h>
#include <math.h>

typedef unsigned short u16;
typedef __bf16 bf16x8 __attribute__((ext_vector_type(8)));
typedef float f32x4  __attribute__((ext_vector_type(4)));
typedef float f32x16 __attribute__((ext_vector_type(16)));
typedef u16   u16x4  __attribute__((ext_vector_type(4)));
typedef u16   u16x8  __attribute__((ext_vector_type(8)));

__device__ __forceinline__ float bf2f(u16 h) { return __uint_as_float(((unsigned)h) << 16); }
__device__ __forceinline__ u16 f2bf(float f) {
    unsigned u = __float_as_uint(f);
    return (u16)((u + 0x7fffu + ((u >> 16) & 1u)) >> 16);
}
// tanh-form gelu, ~8 VALU ops
__device__ __forceinline__ float gelu_f(float x) {
    float u = 0.7978845608f * x * (1.0f + 0.044715f * x * x);
    float e = __expf(2.0f * u);
    float t = 1.0f - 2.0f / (e + 1.0f);
    return 0.5f * x * (1.0f + t);
}

// ---------------------------------------------------------------------------
// Granule layout for X[R rows][K] bf16 (used for BOTH GEMM operands):
//   block (rt=row/32, kt=k/16) = 512 u16 at offset rt*(K/16)*512 + kt*512;
//   lane l, j: row = rt*32+(l&31), k = kt*16+(l>>5)*8+j, off = l*8+j.
// One granule block == one mfma_f32_32x32x16_bf16 operand fragment at lane*8.
//
// Barrier-free register GEMM: C = epi(A(MxK) @ B(NxK)^T), fp32 acc.
// 128x128 tile, 4 waves of 64x64. Per BK=64 iter: 16 coalesced
// global_load_dwordx4 into VGPRs + 16 MFMA. NO LDS / NO __syncthreads in the
// loop -> compiler emits fine-grained vmcnt(N) interleave; waves never block
// each other. LDS (16KB) used only for private per-wave epilogue slices.
// MODE: 0 plain bf16 | 1 scale+granule-out | 2 +bias plain bf16
//       3 +bias,gelu,granule-out | 4 +bias,gelu,+granule-addend,granule-out
//       5 +bias fp32 plain | 6 qkv: +bias,gelu -> q/k granule, v granule^T
// ---------------------------------------------------------------------------
template<int MODE>
__global__ __launch_bounds__(256, 3)
void gemm_r(const u16* __restrict__ A, long sA,
            const u16* __restrict__ B, long sB,
            void* __restrict__ Cout, int ldc, long sC,
            const float* __restrict__ bias,
            const u16* __restrict__ addend,
            u16* __restrict__ g1, u16* __restrict__ g2,
            int K, int Kout, float scale)
{
    __shared__ float sw[4096];          // 16KB: 4 waves x 4KB epilogue slice
    const int t    = threadIdx.x;
    const int lane = t & 63;
    const int wid  = t >> 6;
    const int wm   = (wid & 1) * 64;
    const int wn   = (wid >> 1) * 64;
    const int m32  = lane & 31;
    const int h    = lane >> 5;
    const int bz   = blockIdx.z;

    const long rowA0 = (long)blockIdx.y * 128;
    const long colB0 = (long)blockIdx.x * 128;
    const long ktn  = (long)(K >> 4) * 512;

    const u16* ga0 = A + (long)bz * sA + ((rowA0 + wm) >> 5) * ktn + lane * 8;
    const u16* ga1 = ga0 + ktn;
    const u16* gb0 = B + (long)bz * sB + ((colB0 + wn) >> 5) * ktn + lane * 8;
    const u16* gb1 = gb0 + ktn;

    f32x16 acc[2][2];
    #pragma unroll
    for (int i = 0; i < 2; i++)
        #pragma unroll
        for (int j = 0; j < 2; j++)
            #pragma unroll
            for (int r = 0; r < 16; r++) acc[i][j][r] = 0.f;

    const int ktotal = K >> 4;
    for (int kt = 0; kt < ktotal; kt += 4) {
        const long o = (long)kt * 512;
        bf16x8 a0[4], a1[4], b0[4], b1[4];
        #pragma unroll
        for (int j = 0; j < 4; j++) {
            a0[j] = *(const bf16x8*)(ga0 + o + j * 512);
            a1[j] = *(const bf16x8*)(ga1 + o + j * 512);
            b0[j] = *(const bf16x8*)(gb0 + o + j * 512);
            b1[j] = *(const bf16x8*)(gb1 + o + j * 512);
        }
        #pragma unroll
        for (int j = 0; j < 4; j++) {
            acc[0][0] = __builtin_amdgcn_mfma_f32_32x32x16_bf16(a0[j], b0[j], acc[0][0], 0, 0, 0);
            acc[0][1] = __builtin_amdgcn_mfma_f32_32x32x16_bf16(a0[j], b1[j], acc[0][1], 0, 0, 0);
            acc[1][0] = __builtin_amdgcn_mfma_f32_32x32x16_bf16(a1[j], b0[j], acc[1][0], 0, 0, 0);
            acc[1][1] = __builtin_amdgcn_mfma_f32_32x32x16_bf16(a1[j], b1[j], acc[1][1], 0, 0, 0);
        }
    }

    float* Cf = (float*)Cout + (long)bz * sC;
    u16*   Cu = (u16*)Cout + (long)bz * sC;
    float* sw_ = sw + wid * 1024;       // private slice, no barrier needed
    const long rb = rowA0 + wm;
    const long cb = colB0 + wn;
    const int prow = lane >> 3;
    const int c4   = (lane & 7) * 4;
    const int key  = (m32 & 3) * 8;
    // C/D layout: col = lane&31, row = (r&3)+8*(r>>2)+4*h
    // slice stored col-swizzled: col' = col ^ ((row&3)*8)
    #pragma unroll
    for (int mi = 0; mi < 2; mi++) {
        #pragma unroll
        for (int ni = 0; ni < 2; ni++) {
            const int colg = (int)(cb + ni * 32 + m32);
            float bv = 0.0f;
            if constexpr (MODE >= 2) bv = bias[colg];
            #pragma unroll
            for (int r = 0; r < 16; r++) {
                float v = acc[mi][ni][r];
                if constexpr (MODE == 1) v *= scale;
                v += bv;
                if constexpr (MODE == 3 || MODE == 4 || MODE == 6) v = gelu_f(v);
                const int rowfn = (r & 3) + 8 * (r >> 2) + 4 * h;
                sw_[rowfn * 32 + (m32 ^ ((rowfn & 3) * 8))] = v;
            }
            if constexpr (MODE == 0 || MODE == 2 || MODE == 5) {
                #pragma unroll
                for (int p = 0; p < 4; p++) {
                    const int  row  = p * 8 + prow;
                    const long grow = rb + mi * 32 + row;
                    const long gcol = cb + ni * 32 + c4;
                    const int  k2   = (row & 3) * 8;
                    f32x4 v = *(const f32x4*)&sw_[row * 32 + (c4 ^ k2)];
                    if constexpr (MODE == 5) {
                        *(f32x4*)&Cf[grow * (long)ldc + gcol] = v;
                    } else {
                        u16x4 o = { f2bf(v[0]), f2bf(v[1]), f2bf(v[2]), f2bf(v[3]) };
                        *(u16x4*)&Cu[grow * (long)ldc + gcol] = o;
                    }
                }
            } else if constexpr (MODE == 1 || MODE == 3 || MODE == 4) {
                // granule-out (+optional granule addend)
                const int mt  = (int)((rb + mi * 32) >> 5);
                const int kt0 = (int)((cb + ni * 32) >> 4);
                const long go = (long)bz * sC + ((long)(mt * (Kout >> 4) + kt0)) * 512 + lane * 8;
                u16* dst = g1 + go;
                #pragma unroll
                for (int q2 = 0; q2 < 2; q2++) {
                    const int g0 = q2 * 16 + h * 8;
                    f32x4 u0 = *(const f32x4*)&sw_[m32 * 32 + (g0 ^ key)];
                    f32x4 u1 = *(const f32x4*)&sw_[m32 * 32 + (g0 ^ key) + 4];
                    float vv[8] = { u0[0], u0[1], u0[2], u0[3], u1[0], u1[1], u1[2], u1[3] };
                    if constexpr (MODE == 4) {
                        u16x8 ad = *(const u16x8*)(addend + go + q2 * 512);
                        #pragma unroll
                        for (int e = 0; e < 8; e++) vv[e] += bf2f(ad[e]);
                    }
                    u16x8 o = { f2bf(vv[0]), f2bf(vv[1]), f2bf(vv[2]), f2bf(vv[3]),
                                f2bf(vv[4]), f2bf(vv[5]), f2bf(vv[6]), f2bf(vv[7]) };
                    *(u16x8*)(dst + q2 * 512) = o;
                }
            } else {
                // MODE 6: qkv — seg by output column block
                const int seg = (int)(colB0 >> 10);
                const int b   = (int)(rb >> 11);
                const int rowb = (int)(rb & 2047) + mi * 32;
                if (seg < 2) {
                    // q (seg0) / k (seg1): granule, row=t, k=c
                    const int mt  = rowb >> 5;
                    const int kt0 = ((int)cb + ni * 32 - seg * 1024) >> 4;
                    u16* dst = (seg == 0 ? (u16*)Cout : g1)
                             + (long)b * 2097152 + ((long)(mt * 64 + kt0)) * 512 + lane * 8;
                    #pragma unroll
                    for (int q2 = 0; q2 < 2; q2++) {
                        const int g0 = q2 * 16 + h * 8;
                        f32x4 u0 = *(const f32x4*)&sw_[m32 * 32 + (g0 ^ key)];
                        f32x4 u1 = *(const f32x4*)&sw_[m32 * 32 + (g0 ^ key) + 4];
                        u16x8 o = { f2bf(u0[0]), f2bf(u0[1]), f2bf(u0[2]), f2bf(u0[3]),
                                    f2bf(u1[0]), f2bf(u1[1]), f2bf(u1[2]), f2bf(u1[3]) };
                        *(u16x8*)(dst + q2 * 512) = o;
                    }
                } else {
                    // v: transposed granule, row(n)=c, k=t
                    const int kt0 = rowb >> 4;
                    const int nt  = ((int)cb + ni * 32 - 2048) >> 5;
                    u16* dst = g2 + (long)b * 2097152 + ((long)(nt * 128 + kt0)) * 512 + lane * 8;
                    #pragma unroll
                    for (int q2 = 0; q2 < 2; q2++) {
                        float vv[8];
                        #pragma unroll
                        for (int j = 0; j < 8; j++) {
                            const int r = q2 * 16 + h * 8 + j;
                            vv[j] = sw_[r * 32 + (m32 ^ ((r & 3) * 8))];
                        }
                        u16x8 o = { f2bf(vv[0]), f2bf(vv[1]), f2bf(vv[2]), f2bf(vv[3]),
                                    f2bf(vv[4]), f2bf(vv[5]), f2bf(vv[6]), f2bf(vv[7]) };
                        *(u16x8*)(dst + q2 * 512) = o;
                    }
                }
            }
        }
    }
}

// fp32 [rows][1024] -> bf16 granule, all six arrays in one launch.
// nt segments: x 256 | qkv 384 | proj 128 | fc_in 32 | fc_out 32
__global__ __launch_bounds__(256)
void cvt_a(const float* __restrict__ xs, u16* __restrict__ dx,
           const float* __restrict__ qkvw, u16* __restrict__ dqkv,
           const float* __restrict__ projw, u16* __restrict__ dproj,
           const float* __restrict__ fciw, u16* __restrict__ dfci,
           const float* __restrict__ fcow, u16* __restrict__ dfco)
{
    __shared__ u16 sl[2048];
    const int nt = blockIdx.y;
    const int ks = blockIdx.x;
    const int t  = threadIdx.x;
    const float* src; u16* dst; int nl;
    if      (nt < 256) { src = xs;    dst = dx;    nl = nt; }
    else if (nt < 640) { src = qkvw;  dst = dqkv;  nl = nt - 256; }
    else if (nt < 768) { src = projw; dst = dproj; nl = nt - 640; }
    else if (nt < 800) { src = fciw;  dst = dfci;  nl = nt - 768; }
    else               { src = fcow;  dst = dfco;  nl = nt - 800; }
    const int n32 = t >> 3;
    const int kq  = t & 7;
    const float* s = src + ((long)nl * 32 + n32) * 1024 + ks * 64 + kq * 8;
    float4 v0 = *(const float4*)s;
    float4 v1 = *(const float4*)(s + 4);
    u16x8 o = { f2bf(v0.x), f2bf(v0.y), f2bf(v0.z), f2bf(v0.w),
                f2bf(v1.x), f2bf(v1.y), f2bf(v1.z), f2bf(v1.w) };
    const int slot = (kq >> 1) * 64 + (kq & 1) * 32 + n32;
    *(u16x8*)&sl[slot * 8] = o;
    __syncthreads();
    u16* d = dst + (long)nl * 32768 + ks * 2048 + t * 8;
    *(u16x8*)d = *(const u16x8*)&sl[t * 8];
}

// granule write offset for element (row r, k0..k0+3), K=1024
__device__ __forceinline__ long gr_off(int r, int k0) {
    return (long)(r >> 5) * 32768 + (k0 >> 4) * 512
         + (((k0 >> 3) & 1) * 32 + (r & 31)) * 8 + (k0 & 7);
}

// plain in -> layernorm -> granule out
__global__ __launch_bounds__(256)
void ln_kernel(const u16* __restrict__ in, u16* __restrict__ out,
               const float* __restrict__ g, const float* __restrict__ b)
{
    const int row = blockIdx.x;
    const int t = threadIdx.x;
    const int k0 = t * 4;
    u16x4 xv = *(const u16x4*)&in[(long)row * 1024 + k0];
    float x[4];
    float s = 0.f, s2 = 0.f;
    #pragma unroll
    for (int j = 0; j < 4; j++) { x[j] = bf2f(xv[j]); s += x[j]; s2 += x[j] * x[j]; }
    __shared__ float sm[8];
    const int lane = t & 63, wid = t >> 6;
    #pragma unroll
    for (int o = 32; o > 0; o >>= 1) { s += __shfl_down(s, o, 64); s2 += __shfl_down(s2, o, 64); }
    if (lane == 0) { sm[wid] = s; sm[4 + wid] = s2; }
    __syncthreads();
    s  = sm[0] + sm[1] + sm[2] + sm[3];
    s2 = sm[4] + sm[5] + sm[6] + sm[7];
    const float mean = s * (1.f / 1024.f);
    const float var  = s2 * (1.f / 1024.f) - mean * mean;
    const float rstd = rsqrtf(var + 1e-5f);
    u16x4 o4;
    #pragma unroll
    for (int j = 0; j < 4; j++)
        o4[j] = f2bf((x[j] - mean) * rstd * g[k0 + j] + b[k0 + j]);
    *(u16x4*)&out[gr_off(row, k0)] = o4;
}

// plain in -> softmax -> granule out
__global__ __launch_bounds__(256)
void softmax_kernel(const u16* __restrict__ in, u16* __restrict__ out)
{
    const int row = blockIdx.x;
    const int t = threadIdx.x;
    const int k0 = t * 4;
    u16x4 xv = *(const u16x4*)&in[(long)row * 1024 + k0];
    float x[4];
    float m = -1e30f;
    #pragma unroll
    for (int j = 0; j < 4; j++) { x[j] = bf2f(xv[j]); m = fmaxf(m, x[j]); }
    __shared__ float sm[8];
    const int lane = t & 63, wid = t >> 6;
    #pragma unroll
    for (int o = 32; o > 0; o >>= 1) m = fmaxf(m, __shfl_down(m, o, 64));
    if (lane == 0) sm[wid] = m;
    __syncthreads();
    m = fmaxf(fmaxf(sm[0], sm[1]), fmaxf(sm[2], sm[3]));
    float e[4];
    float s = 0.f;
    #pragma unroll
    for (int j = 0; j < 4; j++) { e[j] = __expf(x[j] - m); s += e[j]; }
    #pragma unroll
    for (int o = 32; o > 0; o >>= 1) s += __shfl_down(s, o, 64);
    if (lane == 0) sm[4 + wid] = s;
    __syncthreads();
    s = sm[4] + sm[5] + sm[6] + sm[7];
    const float inv = 1.f / s;
    u16x4 o4;
    #pragma unroll
    for (int j = 0; j < 4; j++) o4[j] = f2bf(e[j] * inv);
    *(u16x4*)&out[gr_off(row, k0)] = o4;
}

__global__ __launch_bounds__(256)
void add_pe(float* __restrict__ out)
{
    long i = (long)blockIdx.x * 256 + threadIdx.x;
    const int f = (int)(i & 1023);
    const int s = (int)((i >> 10) & 2047);
    const float div = __expf(-(float)f * 0.013491709529261986f);
    const float arg = (float)s * div;
    const float pe = (s & 1) ? cosf(arg) : sinf(arg);
    out[i] += pe;
}

extern "C" void kernel_launch(void* const* d_in, const int* in_sizes, int n_in,
                              void* d_out, int out_size, void* d_ws, size_t ws_size,
                              hipStream_t stream)
{
    const float* x        = (const float*)d_in[0];
    const float* fc_in_w  = (const float*)d_in[1];
    const float* fc_in_b  = (const float*)d_in[2];
    const float* ln_g     = (const float*)d_in[3];
    const float* ln_b     = (const float*)d_in[4];
    const float* qkv_w    = (const float*)d_in[5];
    const float* qkv_b    = (const float*)d_in[6];
    const float* proj_w   = (const float*)d_in[7];
    const float* proj_b   = (const float*)d_in[8];
    const float* fc_out_w = (const float*)d_in[9];
    const float* fc_out_b = (const float*)d_in[10];

    char* w = (char*)d_ws;
    size_t off = 0;
    auto carve = [&](size_t bytes) -> void* {
        void* p = w + off;
        off += (bytes + 255) & ~(size_t)255;
        return p;
    };
    u16* xb   = (u16*)carve(16777216);  // x granule; reused as hY
    u16* hY   = xb;
    u16* wfci = (u16*)carve(2097152);
    u16* wqkv = (u16*)carve(25165824);
    u16* wprj = (u16*)carve(8388608);
    u16* wfco = (u16*)carve(2097152);
    u16* qb   = (u16*)carve(16777216);  // q granule (B,2048 rows,K1024)
    u16* kgr  = (u16*)carve(16777216);  // k granule
    u16* vgr  = (u16*)carve(16777216);  // v^T granule (B,1024 rows,K2048)
    u16* att  = (u16*)carve(16777216);  // plain; also fc_in temp
    u16* attg = (u16*)carve(16777216);  // att granule (rows 8192, K1024)
    u16* hX   = (u16*)carve(16777216);  // granule
    u16* pred = (u16*)carve(16777216);  // granule
    u16* sc   = (u16*)carve(67108864);  // scores granule (B, 2048 rows, K2048)

    cvt_a<<<dim3(16, 832), dim3(256), 0, stream>>>(
        x, xb, qkv_w, wqkv, proj_w, wprj, fc_in_w, wfci, fc_out_w, wfco);

    // fc_in: att(plain temp) = x @ fc_in_w^T + b ; then LN -> hX (granule)
    gemm_r<2><<<dim3(8, 64, 1), 256, 0, stream>>>(xb, 0, wfci, 0,
        att, 1024, 0, fc_in_b, nullptr, nullptr, nullptr, 1024, 0, 1.0f);
    ln_kernel<<<8192, 256, 0, stream>>>(att, hX, ln_g, ln_b);

    const u16* hin[4] = { hX, pred, hX, hY };
    u16* hout[4]      = { pred, hX, hY, hX };

    for (int i = 0; i < 4; i++) {
        // qkv = gelu(h @ qkv_w[i]^T + b): q->qb, k->kgr (granule), v->vgr (granule^T)
        gemm_r<6><<<dim3(24, 64, 1), 256, 0, stream>>>(hin[i], 0,
            wqkv + (long)i * 3145728, 0, qb, 0, 0,
            qkv_b + (long)i * 3072, nullptr, kgr, vgr, 1024, 0, 1.0f);
        // scores = q @ k^T * (1/C) -> granule (A of att GEMM), Kout=2048
        gemm_r<1><<<dim3(16, 16, 4), 256, 0, stream>>>(qb, 2097152,
            kgr, 2097152, nullptr, 0, 4194304,
            nullptr, nullptr, sc, nullptr, 1024, 2048, 1.0f / 1024.0f);
        // att = scores @ v -> plain bf16
        gemm_r<0><<<dim3(8, 16, 4), 256, 0, stream>>>(sc, 4194304,
            vgr, 2097152, att, 1024, 2097152,
            nullptr, nullptr, nullptr, nullptr, 2048, 0, 1.0f);
        // softmax over C -> granule
        softmax_kernel<<<8192, 256, 0, stream>>>(att, attg);
        // h = gelu(attg @ proj_w[i]^T + b) [+ pred] -> granule
        if (i == 0)
            gemm_r<3><<<dim3(8, 64, 1), 256, 0, stream>>>(attg, 0,
                wprj, 0, nullptr, 0, 0, proj_b, nullptr, hout[0], nullptr,
                1024, 1024, 1.0f);
        else
            gemm_r<4><<<dim3(8, 64, 1), 256, 0, stream>>>(attg, 0,
                wprj + (long)i * 1048576, 0, nullptr, 0, 0,
                proj_b + (long)i * 1024, pred, hout[i], nullptr,
                1024, 1024, 1.0f);
    }

    // out = hX @ fc_out_w^T + b (fp32 plain) + pose enc
    gemm_r<5><<<dim3(8, 64, 1), 256, 0, stream>>>(hX, 0, wfco, 0,
        d_out, 1024, 0, fc_out_b, nullptr, nullptr, nullptr, 1024, 0, 1.0f);
    add_pe<<<32768, 256, 0, stream>>>((float*)d_out);
}

// Round 8
// 972.374 us; speedup vs baseline: 1.1280x; 1.1280x over previous
//
#include <hip/hip_runtime.h>
#include <math.h>

typedef unsigned short u16;
typedef __bf16 bf16x8 __attribute__((ext_vector_type(8)));
typedef float f32x4  __attribute__((ext_vector_type(4)));
typedef float f32x16 __attribute__((ext_vector_type(16)));
typedef u16   u16x4  __attribute__((ext_vector_type(4)));
typedef u16   u16x8  __attribute__((ext_vector_type(8)));

__device__ __forceinline__ float bf2f(u16 h) { return __uint_as_float(((unsigned)h) << 16); }
__device__ __forceinline__ u16 f2bf(float f) {
    unsigned u = __float_as_uint(f);
    return (u16)((u + 0x7fffu + ((u >> 16) & 1u)) >> 16);
}
// tanh-form gelu, ~8 VALU ops
__device__ __forceinline__ float gelu_f(float x) {
    float u = 0.7978845608f * x * (1.0f + 0.044715f * x * x);
    float e = __expf(2.0f * u);
    float t = 1.0f - 2.0f / (e + 1.0f);
    return 0.5f * x * (1.0f + t);
}

// ---------------------------------------------------------------------------
// Granule layout for X[R rows][K] bf16 (BOTH GEMM operands):
//   block (rt=row/32, kt=k/16) = 512 u16 at offset rt*(K/16)*512 + kt*512;
//   lane l, j: row = rt*32+(l&31), k = kt*16+(l>>5)*8+j, off = l*8+j.
// One granule block == one mfma_f32_32x32x16_bf16 operand fragment at lane*8.
//
// Barrier-free register GEMM: C = epi(A(MxK) @ B(NxK)^T), fp32 acc.
// 128x128 tile, 4 waves of 64x64; 16 coalesced dwordx4 + 16 MFMA per BK=64.
// No LDS / no __syncthreads in the loop. LDS only for private epilogue slices.
// MODE: 0 plain bf16 | 1 scale+granule-out | 2 +bias plain bf16
//       3 +bias,gelu,granule-out | 4 +bias,gelu,+granule-addend,granule-out
//       5 +bias fp32 plain | 6 qkv: +bias,gelu -> q granule, k/v granule^T
// ---------------------------------------------------------------------------
template<int MODE>
__global__ __launch_bounds__(256, 3)
void gemm_r(const u16* __restrict__ A, long sA,
            const u16* __restrict__ B, long sB,
            void* __restrict__ Cout, int ldc, long sC,
            const float* __restrict__ bias,
            const u16* __restrict__ addend,
            u16* __restrict__ g1, u16* __restrict__ g2,
            int K, int Kout, float scale)
{
    __shared__ float sw[4096];          // 16KB: 4 waves x 4KB epilogue slice
    const int t    = threadIdx.x;
    const int lane = t & 63;
    const int wid  = t >> 6;
    const int wm   = (wid & 1) * 64;
    const int wn   = (wid >> 1) * 64;
    const int m32  = lane & 31;
    const int h    = lane >> 5;
    const int bz   = blockIdx.z;

    const long rowA0 = (long)blockIdx.y * 128;
    const long colB0 = (long)blockIdx.x * 128;
    const long ktn  = (long)(K >> 4) * 512;

    const u16* ga0 = A + (long)bz * sA + ((rowA0 + wm) >> 5) * ktn + lane * 8;
    const u16* ga1 = ga0 + ktn;
    const u16* gb0 = B + (long)bz * sB + ((colB0 + wn) >> 5) * ktn + lane * 8;
    const u16* gb1 = gb0 + ktn;

    f32x16 acc[2][2];
    #pragma unroll
    for (int i = 0; i < 2; i++)
        #pragma unroll
        for (int j = 0; j < 2; j++)
            #pragma unroll
            for (int r = 0; r < 16; r++) acc[i][j][r] = 0.f;

    const int ktotal = K >> 4;
    for (int kt = 0; kt < ktotal; kt += 4) {
        const long o = (long)kt * 512;
        bf16x8 a0[4], a1[4], b0[4], b1[4];
        #pragma unroll
        for (int j = 0; j < 4; j++) {
            a0[j] = *(const bf16x8*)(ga0 + o + j * 512);
            a1[j] = *(const bf16x8*)(ga1 + o + j * 512);
            b0[j] = *(const bf16x8*)(gb0 + o + j * 512);
            b1[j] = *(const bf16x8*)(gb1 + o + j * 512);
        }
        #pragma unroll
        for (int j = 0; j < 4; j++) {
            acc[0][0] = __builtin_amdgcn_mfma_f32_32x32x16_bf16(a0[j], b0[j], acc[0][0], 0, 0, 0);
            acc[0][1] = __builtin_amdgcn_mfma_f32_32x32x16_bf16(a0[j], b1[j], acc[0][1], 0, 0, 0);
            acc[1][0] = __builtin_amdgcn_mfma_f32_32x32x16_bf16(a1[j], b0[j], acc[1][0], 0, 0, 0);
            acc[1][1] = __builtin_amdgcn_mfma_f32_32x32x16_bf16(a1[j], b1[j], acc[1][1], 0, 0, 0);
        }
    }

    float* Cf = (float*)Cout + (long)bz * sC;
    u16*   Cu = (u16*)Cout + (long)bz * sC;
    float* sw_ = sw + wid * 1024;       // private slice, no barrier needed
    const long rb = rowA0 + wm;
    const long cb = colB0 + wn;
    const int prow = lane >> 3;
    const int c4   = (lane & 7) * 4;
    const int key  = (m32 & 3) * 8;
    // C/D layout: col = lane&31, row = (r&3)+8*(r>>2)+4*h
    // slice stored col-swizzled: col' = col ^ ((row&3)*8)
    #pragma unroll
    for (int mi = 0; mi < 2; mi++) {
        #pragma unroll
        for (int ni = 0; ni < 2; ni++) {
            const int colg = (int)(cb + ni * 32 + m32);
            float bv = 0.0f;
            if constexpr (MODE >= 2) bv = bias[colg];
            #pragma unroll
            for (int r = 0; r < 16; r++) {
                float v = acc[mi][ni][r];
                if constexpr (MODE == 1) v *= scale;
                v += bv;
                if constexpr (MODE == 3 || MODE == 4 || MODE == 6) v = gelu_f(v);
                const int rowfn = (r & 3) + 8 * (r >> 2) + 4 * h;
                sw_[rowfn * 32 + (m32 ^ ((rowfn & 3) * 8))] = v;
            }
            if constexpr (MODE == 0 || MODE == 2 || MODE == 5) {
                #pragma unroll
                for (int p = 0; p < 4; p++) {
                    const int  row  = p * 8 + prow;
                    const long grow = rb + mi * 32 + row;
                    const long gcol = cb + ni * 32 + c4;
                    const int  k2   = (row & 3) * 8;
                    f32x4 v = *(const f32x4*)&sw_[row * 32 + (c4 ^ k2)];
                    if constexpr (MODE == 5) {
                        *(f32x4*)&Cf[grow * (long)ldc + gcol] = v;
                    } else {
                        u16x4 o = { f2bf(v[0]), f2bf(v[1]), f2bf(v[2]), f2bf(v[3]) };
                        *(u16x4*)&Cu[grow * (long)ldc + gcol] = o;
                    }
                }
            } else if constexpr (MODE == 1 || MODE == 3 || MODE == 4) {
                // straight granule-out (+optional granule addend)
                const int mt  = (int)((rb + mi * 32) >> 5);
                const int kt0 = (int)((cb + ni * 32) >> 4);
                const long go = (long)bz * sC + ((long)(mt * (Kout >> 4) + kt0)) * 512 + lane * 8;
                u16* dst = g1 + go;
                #pragma unroll
                for (int q2 = 0; q2 < 2; q2++) {
                    const int g0 = q2 * 16 + h * 8;
                    f32x4 u0 = *(const f32x4*)&sw_[m32 * 32 + (g0 ^ key)];
                    f32x4 u1 = *(const f32x4*)&sw_[m32 * 32 + (g0 ^ key) + 4];
                    float vv[8] = { u0[0], u0[1], u0[2], u0[3], u1[0], u1[1], u1[2], u1[3] };
                    if constexpr (MODE == 4) {
                        u16x8 ad = *(const u16x8*)(addend + go + q2 * 512);
                        #pragma unroll
                        for (int e = 0; e < 8; e++) vv[e] += bf2f(ad[e]);
                    }
                    u16x8 o = { f2bf(vv[0]), f2bf(vv[1]), f2bf(vv[2]), f2bf(vv[3]),
                                f2bf(vv[4]), f2bf(vv[5]), f2bf(vv[6]), f2bf(vv[7]) };
                    *(u16x8*)(dst + q2 * 512) = o;
                }
            } else {
                // MODE 6: qkv — seg by output column block
                const int seg  = (int)(colB0 >> 10);
                const int b    = (int)(rb >> 11);
                const int rowb = (int)(rb & 2047) + mi * 32;
                if (seg == 0) {
                    // q: straight granule, row=t, k=c (Kout=1024)
                    const int mt  = rowb >> 5;
                    const int kt0 = ((int)cb + ni * 32) >> 4;
                    u16* dst = (u16*)Cout + (long)b * 2097152
                             + ((long)(mt * 64 + kt0)) * 512 + lane * 8;
                    #pragma unroll
                    for (int q2 = 0; q2 < 2; q2++) {
                        const int g0 = q2 * 16 + h * 8;
                        f32x4 u0 = *(const f32x4*)&sw_[m32 * 32 + (g0 ^ key)];
                        f32x4 u1 = *(const f32x4*)&sw_[m32 * 32 + (g0 ^ key) + 4];
                        u16x8 o = { f2bf(u0[0]), f2bf(u0[1]), f2bf(u0[2]), f2bf(u0[3]),
                                    f2bf(u1[0]), f2bf(u1[1]), f2bf(u1[2]), f2bf(u1[3]) };
                        *(u16x8*)(dst + q2 * 512) = o;
                    }
                } else {
                    // k (seg1) / v (seg2): transposed granule, row(n)=c, k=t (Kout=2048)
                    const int kt0 = rowb >> 4;
                    const int nt  = ((int)cb + ni * 32 - seg * 1024) >> 5;
                    u16* dst = (seg == 1 ? g1 : g2) + (long)b * 2097152
                             + ((long)(nt * 128 + kt0)) * 512 + lane * 8;
                    #pragma unroll
                    for (int q2 = 0; q2 < 2; q2++) {
                        float vv[8];
                        #pragma unroll
                        for (int j = 0; j < 8; j++) {
                            const int r = q2 * 16 + h * 8 + j;
                            vv[j] = sw_[r * 32 + (m32 ^ ((r & 3) * 8))];
                        }
                        u16x8 o = { f2bf(vv[0]), f2bf(vv[1]), f2bf(vv[2]), f2bf(vv[3]),
                                    f2bf(vv[4]), f2bf(vv[5]), f2bf(vv[6]), f2bf(vv[7]) };
                        *(u16x8*)(dst + q2 * 512) = o;
                    }
                }
            }
        }
    }
}

// fp32 [rows][1024] -> bf16 granule, all six arrays in one launch.
// nt segments: x 256 | qkv 384 | proj 128 | fc_in 32 | fc_out 32
__global__ __launch_bounds__(256)
void cvt_a(const float* __restrict__ xs, u16* __restrict__ dx,
           const float* __restrict__ qkvw, u16* __restrict__ dqkv,
           const float* __restrict__ projw, u16* __restrict__ dproj,
           const float* __restrict__ fciw, u16* __restrict__ dfci,
           const float* __restrict__ fcow, u16* __restrict__ dfco)
{
    __shared__ u16 sl[2048];
    const int nt = blockIdx.y;
    const int ks = blockIdx.x;
    const int t  = threadIdx.x;
    const float* src; u16* dst; int nl;
    if      (nt < 256) { src = xs;    dst = dx;    nl = nt; }
    else if (nt < 640) { src = qkvw;  dst = dqkv;  nl = nt - 256; }
    else if (nt < 768) { src = projw; dst = dproj; nl = nt - 640; }
    else if (nt < 800) { src = fciw;  dst = dfci;  nl = nt - 768; }
    else               { src = fcow;  dst = dfco;  nl = nt - 800; }
    const int n32 = t >> 3;
    const int kq  = t & 7;
    const float* s = src + ((long)nl * 32 + n32) * 1024 + ks * 64 + kq * 8;
    float4 v0 = *(const float4*)s;
    float4 v1 = *(const float4*)(s + 4);
    u16x8 o = { f2bf(v0.x), f2bf(v0.y), f2bf(v0.z), f2bf(v0.w),
                f2bf(v1.x), f2bf(v1.y), f2bf(v1.z), f2bf(v1.w) };
    const int slot = (kq >> 1) * 64 + (kq & 1) * 32 + n32;
    *(u16x8*)&sl[slot * 8] = o;
    __syncthreads();
    u16* d = dst + (long)nl * 32768 + ks * 2048 + t * 8;
    *(u16x8*)d = *(const u16x8*)&sl[t * 8];
}

// granule write offset for element (row r, k0..k0+3), K=1024
__device__ __forceinline__ long gr_off(int r, int k0) {
    return (long)(r >> 5) * 32768 + (k0 >> 4) * 512
         + (((k0 >> 3) & 1) * 32 + (r & 31)) * 8 + (k0 & 7);
}

// plain in -> layernorm -> granule out
__global__ __launch_bounds__(256)
void ln_kernel(const u16* __restrict__ in, u16* __restrict__ out,
               const float* __restrict__ g, const float* __restrict__ b)
{
    const int row = blockIdx.x;
    const int t = threadIdx.x;
    const int k0 = t * 4;
    u16x4 xv = *(const u16x4*)&in[(long)row * 1024 + k0];
    float x[4];
    float s = 0.f, s2 = 0.f;
    #pragma unroll
    for (int j = 0; j < 4; j++) { x[j] = bf2f(xv[j]); s += x[j]; s2 += x[j] * x[j]; }
    __shared__ float sm[8];
    const int lane = t & 63, wid = t >> 6;
    #pragma unroll
    for (int o = 32; o > 0; o >>= 1) { s += __shfl_down(s, o, 64); s2 += __shfl_down(s2, o, 64); }
    if (lane == 0) { sm[wid] = s; sm[4 + wid] = s2; }
    __syncthreads();
    s  = sm[0] + sm[1] + sm[2] + sm[3];
    s2 = sm[4] + sm[5] + sm[6] + sm[7];
    const float mean = s * (1.f / 1024.f);
    const float var  = s2 * (1.f / 1024.f) - mean * mean;
    const float rstd = rsqrtf(var + 1e-5f);
    u16x4 o4;
    #pragma unroll
    for (int j = 0; j < 4; j++)
        o4[j] = f2bf((x[j] - mean) * rstd * g[k0 + j] + b[k0 + j]);
    *(u16x4*)&out[gr_off(row, k0)] = o4;
}

// plain in -> softmax -> granule out
__global__ __launch_bounds__(256)
void softmax_kernel(const u16* __restrict__ in, u16* __restrict__ out)
{
    const int row = blockIdx.x;
    const int t = threadIdx.x;
    const int k0 = t * 4;
    u16x4 xv = *(const u16x4*)&in[(long)row * 1024 + k0];
    float x[4];
    float m = -1e30f;
    #pragma unroll
    for (int j = 0; j < 4; j++) { x[j] = bf2f(xv[j]); m = fmaxf(m, x[j]); }
    __shared__ float sm[8];
    const int lane = t & 63, wid = t >> 6;
    #pragma unroll
    for (int o = 32; o > 0; o >>= 1) m = fmaxf(m, __shfl_down(m, o, 64));
    if (lane == 0) sm[wid] = m;
    __syncthreads();
    m = fmaxf(fmaxf(sm[0], sm[1]), fmaxf(sm[2], sm[3]));
    float e[4];
    float s = 0.f;
    #pragma unroll
    for (int j = 0; j < 4; j++) { e[j] = __expf(x[j] - m); s += e[j]; }
    #pragma unroll
    for (int o = 32; o > 0; o >>= 1) s += __shfl_down(s, o, 64);
    if (lane == 0) sm[4 + wid] = s;
    __syncthreads();
    s = sm[4] + sm[5] + sm[6] + sm[7];
    const float inv = 1.f / s;
    u16x4 o4;
    #pragma unroll
    for (int j = 0; j < 4; j++) o4[j] = f2bf(e[j] * inv);
    *(u16x4*)&out[gr_off(row, k0)] = o4;
}

__global__ __launch_bounds__(256)
void add_pe(float* __restrict__ out)
{
    long i = (long)blockIdx.x * 256 + threadIdx.x;
    const int f = (int)(i & 1023);
    const int s = (int)((i >> 10) & 2047);
    const float div = __expf(-(float)f * 0.013491709529261986f);
    const float arg = (float)s * div;
    const float pe = (s & 1) ? cosf(arg) : sinf(arg);
    out[i] += pe;
}

extern "C" void kernel_launch(void* const* d_in, const int* in_sizes, int n_in,
                              void* d_out, int out_size, void* d_ws, size_t ws_size,
                              hipStream_t stream)
{
    const float* x        = (const float*)d_in[0];
    const float* fc_in_w  = (const float*)d_in[1];
    const float* fc_in_b  = (const float*)d_in[2];
    const float* ln_g     = (const float*)d_in[3];
    const float* ln_b     = (const float*)d_in[4];
    const float* qkv_w    = (const float*)d_in[5];
    const float* qkv_b    = (const float*)d_in[6];
    const float* proj_w   = (const float*)d_in[7];
    const float* proj_b   = (const float*)d_in[8];
    const float* fc_out_w = (const float*)d_in[9];
    const float* fc_out_b = (const float*)d_in[10];

    char* w = (char*)d_ws;
    size_t off = 0;
    auto carve = [&](size_t bytes) -> void* {
        void* p = w + off;
        off += (bytes + 255) & ~(size_t)255;
        return p;
    };
    u16* xb   = (u16*)carve(16777216);  // x granule; reused as hY
    u16* hY   = xb;
    u16* wfci = (u16*)carve(2097152);
    u16* wqkv = (u16*)carve(25165824);
    u16* wprj = (u16*)carve(8388608);
    u16* wfco = (u16*)carve(2097152);
    u16* qb   = (u16*)carve(16777216);  // q granule (B, 2048 rows, K1024)
    u16* kgr  = (u16*)carve(16777216);  // k^T granule (B, 1024 rows, K2048)
    u16* vgr  = (u16*)carve(16777216);  // v^T granule (B, 1024 rows, K2048)
    u16* ktg  = (u16*)carve(8388608);   // (v^T k / C) granule (B, 1024 rows, K1024)
    u16* att  = (u16*)carve(16777216);  // plain; also fc_in temp
    u16* attg = (u16*)carve(16777216);  // att granule (8192 rows, K1024)
    u16* hX   = (u16*)carve(16777216);  // granule
    u16* pred = (u16*)carve(16777216);  // granule

    cvt_a<<<dim3(16, 832), dim3(256), 0, stream>>>(
        x, xb, qkv_w, wqkv, proj_w, wprj, fc_in_w, wfci, fc_out_w, wfco);

    // fc_in: att(plain temp) = x @ fc_in_w^T + b ; then LN -> hX (granule)
    gemm_r<2><<<dim3(8, 64, 1), 256, 0, stream>>>(xb, 0, wfci, 0,
        att, 1024, 0, fc_in_b, nullptr, nullptr, nullptr, 1024, 0, 1.0f);
    ln_kernel<<<8192, 256, 0, stream>>>(att, hX, ln_g, ln_b);

    const u16* hin[4] = { hX, pred, hX, hY };
    u16* hout[4]      = { pred, hX, hY, hX };

    for (int i = 0; i < 4; i++) {
        // qkv = gelu(h @ qkv_w[i]^T + b): q->qb (granule), k->kgr, v->vgr (granule^T)
        gemm_r<6><<<dim3(24, 64, 1), 256, 0, stream>>>(hin[i], 0,
            wqkv + (long)i * 3145728, 0, qb, 0, 0,
            qkv_b + (long)i * 3072, nullptr, kgr, vgr, 1024, 0, 1.0f);
        // reassociated attention: ktg[c'][c] = (1/C) * sum_t v[t,c'] k[t,c]
        //   A = v^T granule, B = k^T granule, K=2048 -> granule-out Kout=1024
        gemm_r<1><<<dim3(8, 8, 4), 256, 0, stream>>>(vgr, 2097152,
            kgr, 2097152, nullptr, 0, 1048576,
            nullptr, nullptr, ktg, nullptr, 2048, 1024, 1.0f / 1024.0f);
        // att[s][c'] = sum_c q[s,c] ktg[c'][c]   (A=q granule, B=ktg granule)
        gemm_r<0><<<dim3(8, 16, 4), 256, 0, stream>>>(qb, 2097152,
            ktg, 1048576, att, 1024, 2097152,
            nullptr, nullptr, nullptr, nullptr, 1024, 0, 1.0f);
        // softmax over C -> granule
        softmax_kernel<<<8192, 256, 0, stream>>>(att, attg);
        // h = gelu(attg @ proj_w[i]^T + b) [+ pred] -> granule
        if (i == 0)
            gemm_r<3><<<dim3(8, 64, 1), 256, 0, stream>>>(attg, 0,
                wprj, 0, nullptr, 0, 0, proj_b, nullptr, hout[0], nullptr,
                1024, 1024, 1.0f);
        else
            gemm_r<4><<<dim3(8, 64, 1), 256, 0, stream>>>(attg, 0,
                wprj + (long)i * 1048576, 0, nullptr, 0, 0,
                proj_b + (long)i * 1024, pred, hout[i], nullptr,
                1024, 1024, 1.0f);
    }

    // out = hX @ fc_out_w^T + b (fp32 plain) + pose enc
    gemm_r<5><<<dim3(8, 64, 1), 256, 0, stream>>>(hX, 0, wfco, 0,
        d_out, 1024, 0, fc_out_b, nullptr, nullptr, nullptr, 1024, 0, 1.0f);
    add_pe<<<32768, 256, 0, stream>>>((float*)d_out);
}